// Round 3
// baseline (8479.479 us; speedup 1.0000x reference)
//
#include <hip/hip_runtime.h>
#include <math.h>

#define BB 4
#define LL 4096
#define DD 1024
#define HH 4
#define DKk 256
#define DVv 256
#define HIDD 512
#define NC 128   // number of 32-chunks in L

typedef unsigned short ushort_t;

__device__ __forceinline__ float sigm(float x) { return 1.f / (1.f + __expf(-x)); }

__device__ __forceinline__ float bf2f(ushort_t u) {
  union { unsigned int i; float f; } c; c.i = ((unsigned int)u) << 16; return c.f;
}
__device__ __forceinline__ ushort_t f2bf(float f) {
  union { float f; unsigned int i; } c; c.f = f;
  unsigned int lsb = (c.i >> 16) & 1u;
  return (ushort_t)((c.i + 0x7fffu + lsb) >> 16);
}
__device__ __forceinline__ void unpack2(unsigned int u, float& a, float& b) {
  union { unsigned int i; float f; } c0, c1;
  c0.i = u << 16; c1.i = u & 0xffff0000u; a = c0.f; b = c1.f;
}
__device__ __forceinline__ unsigned int pack2(float a, float b) {
  return (unsigned int)f2bf(a) | ((unsigned int)f2bf(b) << 16);
}
__device__ __forceinline__ void unpack8(const uint4 v, float* o) {
  unpack2(v.x, o[0], o[1]); unpack2(v.y, o[2], o[3]);
  unpack2(v.z, o[4], o[5]); unpack2(v.w, o[6], o[7]);
}

// ---- GEMM: C(M,N)=A(M,K)@W(N,K)^T, A fp32, W fp32, C bf16. ACT1: +bias,silu
template<int ACT>
__global__ __launch_bounds__(256) void gemm_f32_bf16out(const float* __restrict__ A,
    const float* __restrict__ W, const float* __restrict__ bias,
    ushort_t* __restrict__ C, int M, int N, int K)
{
  __shared__ float As[16][128];
  __shared__ float Bs[16][128];
  const int tid = threadIdx.x;
  const int bm = blockIdx.y * 128, bn = blockIdx.x * 128;
  const int lm = tid >> 1, lk = (tid & 1) * 8;
  const int tx = tid & 15, ty = tid >> 4;
  float acc[8][8];
#pragma unroll
  for (int i = 0; i < 8; ++i)
#pragma unroll
    for (int j = 0; j < 8; ++j) acc[i][j] = 0.f;
  const float* Ap = A + (size_t)(bm + lm) * K + lk;
  const float* Wp = W + (size_t)(bn + lm) * K + lk;
  for (int k0 = 0; k0 < K; k0 += 16) {
    const float4 a0 = *(const float4*)(Ap + k0);
    const float4 a1 = *(const float4*)(Ap + k0 + 4);
    const float4 b0 = *(const float4*)(Wp + k0);
    const float4 b1 = *(const float4*)(Wp + k0 + 4);
    __syncthreads();
    As[lk+0][lm]=a0.x; As[lk+1][lm]=a0.y; As[lk+2][lm]=a0.z; As[lk+3][lm]=a0.w;
    As[lk+4][lm]=a1.x; As[lk+5][lm]=a1.y; As[lk+6][lm]=a1.z; As[lk+7][lm]=a1.w;
    Bs[lk+0][lm]=b0.x; Bs[lk+1][lm]=b0.y; Bs[lk+2][lm]=b0.z; Bs[lk+3][lm]=b0.w;
    Bs[lk+4][lm]=b1.x; Bs[lk+5][lm]=b1.y; Bs[lk+6][lm]=b1.z; Bs[lk+7][lm]=b1.w;
    __syncthreads();
#pragma unroll
    for (int kk = 0; kk < 16; ++kk) {
      const float4 am0 = *(const float4*)&As[kk][ty*8];
      const float4 am1 = *(const float4*)&As[kk][ty*8+4];
      const float4 bn0 = *(const float4*)&Bs[kk][tx*8];
      const float4 bn1 = *(const float4*)&Bs[kk][tx*8+4];
      const float am[8] = {am0.x,am0.y,am0.z,am0.w,am1.x,am1.y,am1.z,am1.w};
      const float bv[8] = {bn0.x,bn0.y,bn0.z,bn0.w,bn1.x,bn1.y,bn1.z,bn1.w};
#pragma unroll
      for (int i = 0; i < 8; ++i)
#pragma unroll
        for (int j = 0; j < 8; ++j) acc[i][j] = fmaf(am[i], bv[j], acc[i][j]);
    }
  }
#pragma unroll
  for (int i = 0; i < 8; ++i) {
    ushort_t* Cp = C + (size_t)(bm + ty*8 + i) * N + bn + tx*8;
    float v[8];
#pragma unroll
    for (int j = 0; j < 8; ++j) {
      v[j] = acc[i][j];
      if (ACT == 1) { v[j] += bias[bn + tx*8 + j]; v[j] = v[j] * sigm(v[j]); }
    }
    uint4 pk;
    pk.x = pack2(v[0], v[1]); pk.y = pack2(v[2], v[3]);
    pk.z = pack2(v[4], v[5]); pk.w = pack2(v[6], v[7]);
    *(uint4*)Cp = pk;
  }
}

// ---- GEMM: A bf16, W fp32, C fp32 (final projection) -----------------------
__global__ __launch_bounds__(256) void gemm_bf16A_f32out(const ushort_t* __restrict__ A,
    const float* __restrict__ W, float* __restrict__ C, int M, int N, int K)
{
  __shared__ float As[16][128];
  __shared__ float Bs[16][128];
  const int tid = threadIdx.x;
  const int bm = blockIdx.y * 128, bn = blockIdx.x * 128;
  const int lm = tid >> 1, lk = (tid & 1) * 8;
  const int tx = tid & 15, ty = tid >> 4;
  float acc[8][8];
#pragma unroll
  for (int i = 0; i < 8; ++i)
#pragma unroll
    for (int j = 0; j < 8; ++j) acc[i][j] = 0.f;
  const ushort_t* Ap = A + (size_t)(bm + lm) * K + lk;
  const float* Wp = W + (size_t)(bn + lm) * K + lk;
  for (int k0 = 0; k0 < K; k0 += 16) {
    const uint4 av = *(const uint4*)(Ap + k0);
    const float4 b0 = *(const float4*)(Wp + k0);
    const float4 b1 = *(const float4*)(Wp + k0 + 4);
    float af[8]; unpack8(av, af);
    __syncthreads();
#pragma unroll
    for (int j = 0; j < 8; ++j) As[lk+j][lm] = af[j];
    Bs[lk+0][lm]=b0.x; Bs[lk+1][lm]=b0.y; Bs[lk+2][lm]=b0.z; Bs[lk+3][lm]=b0.w;
    Bs[lk+4][lm]=b1.x; Bs[lk+5][lm]=b1.y; Bs[lk+6][lm]=b1.z; Bs[lk+7][lm]=b1.w;
    __syncthreads();
#pragma unroll
    for (int kk = 0; kk < 16; ++kk) {
      const float4 am0 = *(const float4*)&As[kk][ty*8];
      const float4 am1 = *(const float4*)&As[kk][ty*8+4];
      const float4 bn0 = *(const float4*)&Bs[kk][tx*8];
      const float4 bn1 = *(const float4*)&Bs[kk][tx*8+4];
      const float am[8] = {am0.x,am0.y,am0.z,am0.w,am1.x,am1.y,am1.z,am1.w};
      const float bv[8] = {bn0.x,bn0.y,bn0.z,bn0.w,bn1.x,bn1.y,bn1.z,bn1.w};
#pragma unroll
      for (int i = 0; i < 8; ++i)
#pragma unroll
        for (int j = 0; j < 8; ++j) acc[i][j] = fmaf(am[i], bv[j], acc[i][j]);
    }
  }
#pragma unroll
  for (int i = 0; i < 8; ++i) {
    float* Cp = C + (size_t)(bm + ty*8 + i) * N + bn + tx*8;
#pragma unroll
    for (int j = 0; j < 8; ++j) Cp[j] = acc[i][j];
  }
}

// ---- depthwise causal conv(k=4)+SiLU, bf16 in/out, relayout to (B,H,L,DK) --
__global__ __launch_bounds__(256) void conv_silu_kernel(const ushort_t* __restrict__ xin,
    const float* __restrict__ wc, ushort_t* __restrict__ outp)
{
  const size_t idx = (size_t)blockIdx.x * 256 + threadIdx.x;  // over B*L*D
  const int d = (int)(idx & (DD - 1));
  const int l = (int)((idx >> 10) & (LL - 1));
  const float4 w = *(const float4*)(wc + d * 4);
  const ushort_t* xp = xin + idx;
  float acc = w.w * bf2f(xp[0]);
  if (l >= 1) acc += w.z * bf2f(xp[-DD]);
  if (l >= 2) acc += w.y * bf2f(xp[-2*DD]);
  if (l >= 3) acc += w.x * bf2f(xp[-3*DD]);
  acc = acc * sigm(acc);
  const int b = (int)(idx >> 22);
  const int h = d >> 8, dk = d & 255;
  outp[(((size_t)(b*HH + h))*LL + l)*DKk + dk] = f2bf(acc);
}

// ---- beta / g_s / g_l: 12 length-1024 dots per (b,l), x fp32 ---------------
__global__ __launch_bounds__(256) void small_proj_kernel(const float* __restrict__ x,
   const float* __restrict__ Wb, const float* __restrict__ Wds, const float* __restrict__ bds,
   const float* __restrict__ Wdl, const float* __restrict__ bdl,
   float* __restrict__ beta, float* __restrict__ gs, float* __restrict__ gl)
{
  const int bl = blockIdx.x;
  const int t = threadIdx.x, wave = t >> 6, lane = t & 63;
  __shared__ float res[12];
  const float* xr = x + (size_t)bl * DD + lane * 16;
  const float4 x0 = *(const float4*)(xr);
  const float4 x1 = *(const float4*)(xr + 4);
  const float4 x2 = *(const float4*)(xr + 8);
  const float4 x3 = *(const float4*)(xr + 12);
  for (int rr = 0; rr < 3; ++rr) {
    const int r = wave * 3 + rr;
    const int mat = r >> 2, h = r & 3;
    const float* Wr = (mat == 0 ? Wb : (mat == 1 ? Wds : Wdl)) + (size_t)h * DD + lane * 16;
    const float4 w0 = *(const float4*)(Wr);
    const float4 w1 = *(const float4*)(Wr + 4);
    const float4 w2 = *(const float4*)(Wr + 8);
    const float4 w3 = *(const float4*)(Wr + 12);
    float p = x0.x*w0.x + x0.y*w0.y + x0.z*w0.z + x0.w*w0.w
            + x1.x*w1.x + x1.y*w1.y + x1.z*w1.z + x1.w*w1.w
            + x2.x*w2.x + x2.y*w2.y + x2.z*w2.z + x2.w*w2.w
            + x3.x*w3.x + x3.y*w3.y + x3.z*w3.z + x3.w*w3.w;
#pragma unroll
    for (int o = 1; o < 64; o <<= 1) p += __shfl_xor(p, o);
    if (lane == 0) res[r] = p;
  }
  __syncthreads();
  if (t < 12) {
    const int mat = t >> 2, h = t & 3;
    float v = res[t];
    if (mat == 1) v += bds[h];
    if (mat == 2) v += bdl[h];
    v = sigm(v);
    const int b = bl >> 12, l = bl & (LL - 1);
    const size_t o = ((size_t)(b*HH + h))*LL + l;
    (mat == 0 ? beta : (mat == 1 ? gs : gl))[o] = v;
  }
}

// ---- hierarchical gate: z bf16, 24 length-512 dots + 2-way softmaxes -------
__global__ __launch_bounds__(256) void gate_kernel(const ushort_t* __restrict__ z,
  const float* __restrict__ Wc, const float* __restrict__ bc,
  const float* __restrict__ Wl, const float* __restrict__ bl_,
  const float* __restrict__ Wg, const float* __restrict__ bg,
  const float* __restrict__ ltc, const float* __restrict__ ltf,
  float* __restrict__ wgt)
{
  const int bl = blockIdx.x;
  const int t = threadIdx.x, wave = t >> 6, lane = t & 63;
  __shared__ float res[24];
  const uint4 zv = *(const uint4*)(z + (size_t)bl * HIDD + lane * 8);
  float zf[8]; unpack8(zv, zf);
  for (int rr = 0; rr < 6; ++rr) {
    const int r = wave * 6 + rr;
    const int mat = r >> 3, qi = r & 7;
    const float* Wr = (mat == 0 ? Wc : (mat == 1 ? Wl : Wg)) + (size_t)qi * HIDD + lane * 8;
    const float4 w0 = *(const float4*)(Wr);
    const float4 w1 = *(const float4*)(Wr + 4);
    float p = zf[0]*w0.x + zf[1]*w0.y + zf[2]*w0.z + zf[3]*w0.w
            + zf[4]*w1.x + zf[5]*w1.y + zf[6]*w1.z + zf[7]*w1.w;
#pragma unroll
    for (int o = 1; o < 64; o <<= 1) p += __shfl_xor(p, o);
    if (lane == 0) {
      const float* br = (mat == 0 ? bc : (mat == 1 ? bl_ : bg));
      res[r] = p + br[qi];
    }
  }
  __syncthreads();
  if (t < 4) {
    const float tc = logf(1.f + __expf(ltc[t])) + 1e-4f;
    const float tf = logf(1.f + __expf(ltf[t])) + 1e-4f;
    const float pg0 = sigm((res[2*t]     - res[2*t+1])     / tc);
    const float q0  = sigm((res[8+2*t]   - res[8+2*t+1])   / tf);
    const float r0  = sigm((res[16+2*t]  - res[16+2*t+1])  / tf);
    float* o = wgt + ((size_t)bl * HH + t) * 4;
    o[0] = pg0 * q0;         o[1] = pg0 * (1.f - q0);
    o[2] = (1.f - pg0) * r0; o[3] = (1.f - pg0) * (1.f - r0);
  }
}

// ---- chunk-local prep (bf16 LDS, stride 264): l2norm, attn, solves ---------
#define QS 264
__global__ __launch_bounds__(256) void prep_kernel(ushort_t* __restrict__ q,
    ushort_t* __restrict__ k, const ushort_t* __restrict__ v,
    const float* __restrict__ beta,
    ushort_t* __restrict__ u, ushort_t* __restrict__ w, float* __restrict__ attn)
{
  __shared__ ushort_t qb[32*QS];
  __shared__ ushort_t kb[32*QS];
  __shared__ float Lm[32*32];
  __shared__ float betas[32];
  const int bid = blockIdx.x;
  const int ci = bid & (NC - 1);
  const int bh = bid >> 7;
  const int t = threadIdx.x;
  const size_t base = ((size_t)bh * LL + ci*32) * DKk;
  if (t < 32) betas[t] = beta[(size_t)bh * LL + ci*32 + t];
  // load 32x256 bf16 tiles (uint4 = 8 bf16)
  for (int i4 = t; i4 < 1024; i4 += 256) {
    const int r = i4 >> 5, e = (i4 & 31) * 8;
    *(uint4*)&qb[r*QS + e] = *(const uint4*)(q + base + r*256 + e);
    *(uint4*)&kb[r*QS + e] = *(const uint4*)(k + base + r*256 + e);
  }
  __syncthreads();
  {  // l2norm rows (8 threads per row)
    const int r = t >> 3, g = t & 7;
    float sq = 0.f, sk = 0.f;
    for (int e = g*32; e < g*32 + 32; ++e) {
      const float a = bf2f(qb[r*QS + e]); sq = fmaf(a, a, sq);
      const float c = bf2f(kb[r*QS + e]); sk = fmaf(c, c, sk);
    }
#pragma unroll
    for (int o = 1; o < 8; o <<= 1) { sq += __shfl_xor(sq, o); sk += __shfl_xor(sk, o); }
    const float rq = rsqrtf(sq + 1e-6f), rk = rsqrtf(sk + 1e-6f);
    for (int e = g*32; e < g*32 + 32; ++e) {
      qb[r*QS + e] = f2bf(bf2f(qb[r*QS + e]) * rq);
      kb[r*QS + e] = f2bf(bf2f(kb[r*QS + e]) * rk);
    }
  }
  __syncthreads();
  // write back normalized q,k
  for (int i4 = t; i4 < 1024; i4 += 256) {
    const int r = i4 >> 5, e = (i4 & 31) * 8;
    *(uint4*)(q + base + r*256 + e) = *(const uint4*)&qb[r*QS + e];
    *(uint4*)(k + base + r*256 + e) = *(const uint4*)&kb[r*QS + e];
  }
  {  // attn (inclusive-tril of q@k^T) and Lm = strict-tril(beta_i * k_i.k_j)
    const int j = t & 31, i0 = (t >> 5) * 4;
#pragma unroll
    for (int ii = 0; ii < 4; ++ii) {
      const int i = i0 + ii;
      float dq = 0.f, dk2 = 0.f;
      for (int e = 0; e < 256; ++e) {
        const float kj = bf2f(kb[j*QS + e]);
        dq  = fmaf(bf2f(qb[i*QS + e]), kj, dq);
        dk2 = fmaf(bf2f(kb[i*QS + e]), kj, dk2);
      }
      attn[((size_t)bh*NC + ci)*1024 + i*32 + j] = (j <= i) ? dq : 0.f;
      Lm[i*32 + j] = (j < i) ? betas[i] * dk2 : 0.f;
    }
  }
  __syncthreads();
  {  // forward substitution per column t: u = Tinv (beta*v), w = Tinv (beta*k)
    float cu[32], cw[32];
#pragma unroll
    for (int r = 0; r < 32; ++r) {
      cu[r] = bf2f(v[base + r*256 + t]) * betas[r];
      cw[r] = bf2f(kb[r*QS + t]) * betas[r];
    }
#pragma unroll
    for (int i = 1; i < 32; ++i) {
      float au = cu[i], aw = cw[i];
#pragma unroll
      for (int j = 0; j < i; ++j) {
        const float lm = Lm[i*32 + j];
        au = fmaf(-lm, cu[j], au);
        aw = fmaf(-lm, cw[j], aw);
      }
      cu[i] = au; cw[i] = aw;
    }
#pragma unroll
    for (int r = 0; r < 32; ++r) {
      u[base + r*256 + t] = f2bf(cu[r]);
      w[base + r*256 + t] = f2bf(cw[r]);
    }
  }
}

// ---- sequential chunk scan, S(256x16 slice) in registers, bf16 inputs ------
__global__ __launch_bounds__(256) void scan_kernel(const ushort_t* __restrict__ qn,
  const ushort_t* __restrict__ kn, const ushort_t* __restrict__ u,
  const ushort_t* __restrict__ w, const float* __restrict__ attn,
  float* __restrict__ dout)
{
  __shared__ float uhl[32*16];
  const int bid = blockIdx.x;
  const int vb = bid & 15, bh = bid >> 4;
  const int b = bh >> 2, h = bh & 3;
  const int t = threadIdx.x;
  const int c = t >> 4, g = t & 15;
  const int e0 = g * 16;
  const int dv = vb * 16 + c;
  float S[16];
#pragma unroll
  for (int i = 0; i < 16; ++i) S[i] = 0.f;
  const size_t bhL = (size_t)bh * LL;
  for (int ci = 0; ci < NC; ++ci) {
    const ushort_t* wr = w  + (bhL + ci*32) * DKk + e0;
    const ushort_t* qr = qn + (bhL + ci*32) * DKk + e0;
    const ushort_t* kr = kn + (bhL + ci*32) * DKk + e0;
    const ushort_t* ur = u  + (bhL + ci*32) * DVv + dv;
    const float* ar = attn + ((size_t)bh*NC + ci) * 1024;
#pragma unroll 4
    for (int r = 0; r < 32; ++r) {
      const uint4 w0 = *(const uint4*)(wr + r*DKk);
      const uint4 w1 = *(const uint4*)(wr + r*DKk + 8);
      float a[16]; unpack8(w0, a); unpack8(w1, a+8);
      float p = 0.f;
#pragma unroll
      for (int i = 0; i < 16; ++i) p = fmaf(a[i], S[i], p);
      p += __shfl_xor(p, 1); p += __shfl_xor(p, 2);
      p += __shfl_xor(p, 4); p += __shfl_xor(p, 8);
      const float uh = bf2f(ur[r*DVv]) - p;
      if (g == 0) uhl[r*16 + c] = uh;
    }
#pragma unroll 4
    for (int r = 0; r < 32; ++r) {
      const uint4 q0 = *(const uint4*)(qr + r*DKk);
      const uint4 q1 = *(const uint4*)(qr + r*DKk + 8);
      float a[16]; unpack8(q0, a); unpack8(q1, a+8);
      float p = 0.f;
#pragma unroll
      for (int i = 0; i < 16; ++i) p = fmaf(a[i], S[i], p);
      p = fmaf(ar[r*32 + 2*g],     uhl[(2*g)*16 + c],   p);
      p = fmaf(ar[r*32 + 2*g + 1], uhl[(2*g+1)*16 + c], p);
      p += __shfl_xor(p, 1); p += __shfl_xor(p, 2);
      p += __shfl_xor(p, 4); p += __shfl_xor(p, 8);
      if (g == 0) dout[((size_t)b*LL + ci*32 + r)*DD + h*DVv + dv] = p;
    }
#pragma unroll 4
    for (int r = 0; r < 32; ++r) {
      const uint4 k0 = *(const uint4*)(kr + r*DKk);
      const uint4 k1 = *(const uint4*)(kr + r*DKk + 8);
      float a[16]; unpack8(k0, a); unpack8(k1, a+8);
      const float uh = uhl[r*16 + c];
#pragma unroll
      for (int i = 0; i < 16; ++i) S[i] = fmaf(a[i], uh, S[i]);
    }
  }
}

// ---- dual EMA scan (bf16 v in, bf16 es/el out) -----------------------------
__global__ __launch_bounds__(64) void ema_kernel(const ushort_t* __restrict__ v,
  const float* __restrict__ gs, const float* __restrict__ gl,
  ushort_t* __restrict__ es, ushort_t* __restrict__ el)
{
  const int bid = blockIdx.x;
  const int vb = bid & 3, bh = bid >> 2;
  const int b = bh >> 2, h = bh & 3;
  const int dv = vb * 64 + threadIdx.x;
  const ushort_t* vp  = v + ((size_t)bh * LL) * DVv + dv;
  const float* gsp = gs + (size_t)bh * LL;
  const float* glp = gl + (size_t)bh * LL;
  ushort_t* esp = es + ((size_t)b * LL) * DD + h*DVv + dv;
  ushort_t* elp = el + ((size_t)b * LL) * DD + h*DVv + dv;
  float s1 = 0.f, s2 = 0.f;
  for (int l = 0; l < LL; ++l) {
    const float vv = bf2f(vp[(size_t)l * DVv]);
    const float a = gsp[l], g2 = glp[l];
    s1 = fmaf(a,  s1, (1.f - a)  * vv);
    s2 = fmaf(g2, s2, (1.f - g2) * vv);
    esp[(size_t)l * DD] = f2bf(s1);
    elp[(size_t)l * DD] = f2bf(s2);
  }
}

// ---- combine + per-head RMSNorm (delta_o fp32 from d_out, rest bf16) -------
__global__ __launch_bounds__(64) void combine_kernel(const ushort_t* __restrict__ v,
  const ushort_t* __restrict__ es, const ushort_t* __restrict__ el,
  const float* __restrict__ dov, const float* __restrict__ wgt,
  const float* __restrict__ onw, ushort_t* __restrict__ outp)
{
  const int bid = blockIdx.x;   // (b*L + l)*H + h
  const int h = bid & 3;
  const size_t bl = (size_t)(bid >> 2);
  const int lane = threadIdx.x;
  const size_t b = bl >> 12;
  const size_t l = bl & (LL - 1);
  const size_t vidx = (((b*HH + h) * (size_t)LL) + l) * DVv + lane*4;
  const size_t didx = bl * DD + h*DVv + lane*4;
  const uint2 vu = *(const uint2*)(v + vidx);
  const uint2 eu = *(const uint2*)(es + didx);
  const uint2 gu = *(const uint2*)(el + didx);
  const float4 d4 = *(const float4*)(dov + didx);
  float vf[4], ef[4], gf[4];
  unpack2(vu.x, vf[0], vf[1]); unpack2(vu.y, vf[2], vf[3]);
  unpack2(eu.x, ef[0], ef[1]); unpack2(eu.y, ef[2], ef[3]);
  unpack2(gu.x, gf[0], gf[1]); unpack2(gu.y, gf[2], gf[3]);
  const float* wp = wgt + (size_t)bid * 4;
  const float w0 = wp[0], w1 = wp[1], w2 = wp[2], w3 = wp[3];
  float o[4];
  const float df[4] = {d4.x, d4.y, d4.z, d4.w};
  float ss = 0.f;
#pragma unroll
  for (int i = 0; i < 4; ++i) {
    o[i] = w0*vf[i] + w1*ef[i] + w2*df[i] + w3*gf[i];
    ss = fmaf(o[i], o[i], ss);
  }
#pragma unroll
  for (int off = 1; off < 64; off <<= 1) ss += __shfl_xor(ss, off);
  const float sc = rsqrtf(ss * (1.f / DVv) + 1e-5f);
  const float4 nw = *(const float4*)(onw + lane*4);
  uint2 pk;
  pk.x = pack2(o[0]*sc*nw.x, o[1]*sc*nw.y);
  pk.y = pack2(o[2]*sc*nw.z, o[3]*sc*nw.w);
  *(uint2*)(outp + didx) = pk;
}

extern "C" void kernel_launch(void* const* d_in, const int* in_sizes, int n_in,
                              void* d_out, int out_size, void* d_ws, size_t ws_size,
                              hipStream_t stream)
{
  const float* x    = (const float*)d_in[0];
  const float* Wq   = (const float*)d_in[1];
  const float* Wk   = (const float*)d_in[2];
  const float* Wv   = (const float*)d_in[3];
  const float* cqw  = (const float*)d_in[4];
  const float* ckw  = (const float*)d_in[5];
  const float* cvw  = (const float*)d_in[6];
  const float* Wb   = (const float*)d_in[7];
  const float* Wds  = (const float*)d_in[8];
  const float* bds  = (const float*)d_in[9];
  const float* Wdl  = (const float*)d_in[10];
  const float* bdl  = (const float*)d_in[11];
  const float* Wtr  = (const float*)d_in[12];
  const float* btr  = (const float*)d_in[13];
  const float* Wc   = (const float*)d_in[14];
  const float* bc   = (const float*)d_in[15];
  const float* Wl   = (const float*)d_in[16];
  const float* blc  = (const float*)d_in[17];
  const float* Wg   = (const float*)d_in[18];
  const float* bg   = (const float*)d_in[19];
  const float* ltc  = (const float*)d_in[20];
  const float* ltf  = (const float*)d_in[21];
  const float* onw  = (const float*)d_in[22];
  const float* Wo   = (const float*)d_in[23];
  float* outp = (float*)d_out;

  // bf16 workspace slabs: peak ~186 MB (was 379 MB fp32 -> suspected overflow)
  const size_t BLD = (size_t)BB * LL * DD;          // 16.78M elements
  unsigned char* w8 = (unsigned char*)d_ws;
  const size_t SL = BLD * 2;                        // 32 MB bf16 slab
  ushort_t* SA = (ushort_t*)(w8 + 0*SL);   // qraw -> kn          -> opre
  ushort_t* SB = (ushort_t*)(w8 + 1*SL);   // kraw -> vv
  ushort_t* SC = (ushort_t*)(w8 + 2*SL);   // vraw -> u
  ushort_t* SD = (ushort_t*)(w8 + 3*SL);   // qn           -> el
  ushort_t* SE = (ushort_t*)(w8 + 4*SL);   // w            -> es
  ushort_t* zb   = (ushort_t*)(w8 + 5*SL);               // B*L*512 bf16 (16MB)
  float*    attn = (float*)(w8 + 5*SL + BLD);            // 8 MB
  float*    beta = attn + (size_t)BB*HH*NC*1024;
  float*    gs   = beta + (size_t)BB*HH*LL;
  float*    gl   = gs   + (size_t)BB*HH*LL;
  float*    wgt  = gl   + (size_t)BB*HH*LL;              // 1 MB
  float*    dov  = outp;   // delta_o fp32 in d_out until final GEMM

  const int MBL = BB * LL;  // 16384
  dim3 blk256(256);

  gemm_f32_bf16out<0><<<dim3(DD/128, MBL/128), blk256, 0, stream>>>(x, Wq, nullptr, SA, MBL, DD, DD);
  gemm_f32_bf16out<0><<<dim3(DD/128, MBL/128), blk256, 0, stream>>>(x, Wk, nullptr, SB, MBL, DD, DD);
  gemm_f32_bf16out<0><<<dim3(DD/128, MBL/128), blk256, 0, stream>>>(x, Wv, nullptr, SC, MBL, DD, DD);
  gemm_f32_bf16out<1><<<dim3(HIDD/128, MBL/128), blk256, 0, stream>>>(x, Wtr, btr, zb, MBL, HIDD, DD);
  small_proj_kernel<<<dim3(MBL), blk256, 0, stream>>>(x, Wb, Wds, bds, Wdl, bdl, beta, gs, gl);
  gate_kernel<<<dim3(MBL), blk256, 0, stream>>>(zb, Wc, bc, Wl, blc, Wg, bg, ltc, ltf, wgt);
  conv_silu_kernel<<<dim3((unsigned)(BB*LL*DD/256)), blk256, 0, stream>>>(SA, cqw, SD);  // qn=SD
  conv_silu_kernel<<<dim3((unsigned)(BB*LL*DD/256)), blk256, 0, stream>>>(SB, ckw, SA);  // kn=SA
  conv_silu_kernel<<<dim3((unsigned)(BB*LL*DD/256)), blk256, 0, stream>>>(SC, cvw, SB);  // vv=SB
  prep_kernel<<<dim3(BB*HH*NC), blk256, 0, stream>>>(SD, SA, SB, beta, SC, SE, attn);    // u=SC w=SE
  scan_kernel<<<dim3(BB*HH*16), blk256, 0, stream>>>(SD, SA, SC, SE, attn, dov);
  ema_kernel<<<dim3(BB*HH*4), dim3(64), 0, stream>>>(SB, gs, gl, SE, SD);                // es=SE el=SD
  combine_kernel<<<dim3(MBL*HH), dim3(64), 0, stream>>>(SB, SE, SD, dov, wgt, onw, SA);  // opre=SA
  gemm_bf16A_f32out<<<dim3(DD/128, MBL/128), blk256, 0, stream>>>(SA, Wo, outp, MBL, DD, DD);
}

// Round 4
// 5707.489 us; speedup vs baseline: 1.4857x; 1.4857x over previous
//
#include <hip/hip_runtime.h>
#include <math.h>

#define BB 4
#define LL 4096
#define DD 1024
#define HH 4
#define DKk 256
#define DVv 256
#define HIDD 512
#define NC 128   // number of 32-chunks in L

typedef unsigned short ushort_t;

__device__ __forceinline__ float sigm(float x) { return 1.f / (1.f + __expf(-x)); }

__device__ __forceinline__ float bf2f(ushort_t u) {
  union { unsigned int i; float f; } c; c.i = ((unsigned int)u) << 16; return c.f;
}
__device__ __forceinline__ ushort_t f2bf(float f) {
  union { float f; unsigned int i; } c; c.f = f;
  unsigned int lsb = (c.i >> 16) & 1u;
  return (ushort_t)((c.i + 0x7fffu + lsb) >> 16);
}
__device__ __forceinline__ void unpack2(unsigned int u, float& a, float& b) {
  union { unsigned int i; float f; } c0, c1;
  c0.i = u << 16; c1.i = u & 0xffff0000u; a = c0.f; b = c1.f;
}
__device__ __forceinline__ unsigned int pack2(float a, float b) {
  return (unsigned int)f2bf(a) | ((unsigned int)f2bf(b) << 16);
}
__device__ __forceinline__ void unpack8(const uint4 v, float* o) {
  unpack2(v.x, o[0], o[1]); unpack2(v.y, o[2], o[3]);
  unpack2(v.z, o[4], o[5]); unpack2(v.w, o[6], o[7]);
}

// ---- GEMM: C(M,N)=A(M,K)@W(N,K)^T, A fp32, W fp32, C bf16. ACT1: +bias,silu
template<int ACT>
__global__ __launch_bounds__(256) void gemm_f32_bf16out(const float* __restrict__ A,
    const float* __restrict__ W, const float* __restrict__ bias,
    ushort_t* __restrict__ C, int M, int N, int K)
{
  __shared__ float As[16][128];
  __shared__ float Bs[16][128];
  const int tid = threadIdx.x;
  const int bm = blockIdx.y * 128, bn = blockIdx.x * 128;
  const int lm = tid >> 1, lk = (tid & 1) * 8;
  const int tx = tid & 15, ty = tid >> 4;
  float acc[8][8];
#pragma unroll
  for (int i = 0; i < 8; ++i)
#pragma unroll
    for (int j = 0; j < 8; ++j) acc[i][j] = 0.f;
  const float* Ap = A + (size_t)(bm + lm) * K + lk;
  const float* Wp = W + (size_t)(bn + lm) * K + lk;
  for (int k0 = 0; k0 < K; k0 += 16) {
    const float4 a0 = *(const float4*)(Ap + k0);
    const float4 a1 = *(const float4*)(Ap + k0 + 4);
    const float4 b0 = *(const float4*)(Wp + k0);
    const float4 b1 = *(const float4*)(Wp + k0 + 4);
    __syncthreads();
    As[lk+0][lm]=a0.x; As[lk+1][lm]=a0.y; As[lk+2][lm]=a0.z; As[lk+3][lm]=a0.w;
    As[lk+4][lm]=a1.x; As[lk+5][lm]=a1.y; As[lk+6][lm]=a1.z; As[lk+7][lm]=a1.w;
    Bs[lk+0][lm]=b0.x; Bs[lk+1][lm]=b0.y; Bs[lk+2][lm]=b0.z; Bs[lk+3][lm]=b0.w;
    Bs[lk+4][lm]=b1.x; Bs[lk+5][lm]=b1.y; Bs[lk+6][lm]=b1.z; Bs[lk+7][lm]=b1.w;
    __syncthreads();
#pragma unroll
    for (int kk = 0; kk < 16; ++kk) {
      const float4 am0 = *(const float4*)&As[kk][ty*8];
      const float4 am1 = *(const float4*)&As[kk][ty*8+4];
      const float4 bn0 = *(const float4*)&Bs[kk][tx*8];
      const float4 bn1 = *(const float4*)&Bs[kk][tx*8+4];
      const float am[8] = {am0.x,am0.y,am0.z,am0.w,am1.x,am1.y,am1.z,am1.w};
      const float bv[8] = {bn0.x,bn0.y,bn0.z,bn0.w,bn1.x,bn1.y,bn1.z,bn1.w};
#pragma unroll
      for (int i = 0; i < 8; ++i)
#pragma unroll
        for (int j = 0; j < 8; ++j) acc[i][j] = fmaf(am[i], bv[j], acc[i][j]);
    }
  }
#pragma unroll
  for (int i = 0; i < 8; ++i) {
    ushort_t* Cp = C + (size_t)(bm + ty*8 + i) * N + bn + tx*8;
    float v[8];
#pragma unroll
    for (int j = 0; j < 8; ++j) {
      v[j] = acc[i][j];
      if (ACT == 1) { v[j] += bias[bn + tx*8 + j]; v[j] = v[j] * sigm(v[j]); }
    }
    uint4 pk;
    pk.x = pack2(v[0], v[1]); pk.y = pack2(v[2], v[3]);
    pk.z = pack2(v[4], v[5]); pk.w = pack2(v[6], v[7]);
    *(uint4*)Cp = pk;
  }
}

// ---- GEMM: A bf16, W fp32, C fp32 (final projection) -----------------------
__global__ __launch_bounds__(256) void gemm_bf16A_f32out(const ushort_t* __restrict__ A,
    const float* __restrict__ W, float* __restrict__ C, int M, int N, int K)
{
  __shared__ float As[16][128];
  __shared__ float Bs[16][128];
  const int tid = threadIdx.x;
  const int bm = blockIdx.y * 128, bn = blockIdx.x * 128;
  const int lm = tid >> 1, lk = (tid & 1) * 8;
  const int tx = tid & 15, ty = tid >> 4;
  float acc[8][8];
#pragma unroll
  for (int i = 0; i < 8; ++i)
#pragma unroll
    for (int j = 0; j < 8; ++j) acc[i][j] = 0.f;
  const ushort_t* Ap = A + (size_t)(bm + lm) * K + lk;
  const float* Wp = W + (size_t)(bn + lm) * K + lk;
  for (int k0 = 0; k0 < K; k0 += 16) {
    const uint4 av = *(const uint4*)(Ap + k0);
    const float4 b0 = *(const float4*)(Wp + k0);
    const float4 b1 = *(const float4*)(Wp + k0 + 4);
    float af[8]; unpack8(av, af);
    __syncthreads();
#pragma unroll
    for (int j = 0; j < 8; ++j) As[lk+j][lm] = af[j];
    Bs[lk+0][lm]=b0.x; Bs[lk+1][lm]=b0.y; Bs[lk+2][lm]=b0.z; Bs[lk+3][lm]=b0.w;
    Bs[lk+4][lm]=b1.x; Bs[lk+5][lm]=b1.y; Bs[lk+6][lm]=b1.z; Bs[lk+7][lm]=b1.w;
    __syncthreads();
#pragma unroll
    for (int kk = 0; kk < 16; ++kk) {
      const float4 am0 = *(const float4*)&As[kk][ty*8];
      const float4 am1 = *(const float4*)&As[kk][ty*8+4];
      const float4 bn0 = *(const float4*)&Bs[kk][tx*8];
      const float4 bn1 = *(const float4*)&Bs[kk][tx*8+4];
      const float am[8] = {am0.x,am0.y,am0.z,am0.w,am1.x,am1.y,am1.z,am1.w};
      const float bv[8] = {bn0.x,bn0.y,bn0.z,bn0.w,bn1.x,bn1.y,bn1.z,bn1.w};
#pragma unroll
      for (int i = 0; i < 8; ++i)
#pragma unroll
        for (int j = 0; j < 8; ++j) acc[i][j] = fmaf(am[i], bv[j], acc[i][j]);
    }
  }
#pragma unroll
  for (int i = 0; i < 8; ++i) {
    float* Cp = C + (size_t)(bm + ty*8 + i) * N + bn + tx*8;
#pragma unroll
    for (int j = 0; j < 8; ++j) Cp[j] = acc[i][j];
  }
}

// ---- depthwise causal conv(k=4)+SiLU, bf16 in/out, relayout to (B,H,L,DK) --
__global__ __launch_bounds__(256) void conv_silu_kernel(const ushort_t* __restrict__ xin,
    const float* __restrict__ wc, ushort_t* __restrict__ outp)
{
  const size_t idx = (size_t)blockIdx.x * 256 + threadIdx.x;  // over B*L*D
  const int d = (int)(idx & (DD - 1));
  const int l = (int)((idx >> 10) & (LL - 1));
  const float4 w = *(const float4*)(wc + d * 4);
  const ushort_t* xp = xin + idx;
  float acc = w.w * bf2f(xp[0]);
  if (l >= 1) acc += w.z * bf2f(xp[-DD]);
  if (l >= 2) acc += w.y * bf2f(xp[-2*DD]);
  if (l >= 3) acc += w.x * bf2f(xp[-3*DD]);
  acc = acc * sigm(acc);
  const int b = (int)(idx >> 22);
  const int h = d >> 8, dk = d & 255;
  outp[(((size_t)(b*HH + h))*LL + l)*DKk + dk] = f2bf(acc);
}

// ---- beta / g_s / g_l: 12 length-1024 dots per (b,l), x fp32 ---------------
__global__ __launch_bounds__(256) void small_proj_kernel(const float* __restrict__ x,
   const float* __restrict__ Wb, const float* __restrict__ Wds, const float* __restrict__ bds,
   const float* __restrict__ Wdl, const float* __restrict__ bdl,
   float* __restrict__ beta, float* __restrict__ gs, float* __restrict__ gl)
{
  const int bl = blockIdx.x;
  const int t = threadIdx.x, wave = t >> 6, lane = t & 63;
  __shared__ float res[12];
  const float* xr = x + (size_t)bl * DD + lane * 16;
  const float4 x0 = *(const float4*)(xr);
  const float4 x1 = *(const float4*)(xr + 4);
  const float4 x2 = *(const float4*)(xr + 8);
  const float4 x3 = *(const float4*)(xr + 12);
  for (int rr = 0; rr < 3; ++rr) {
    const int r = wave * 3 + rr;
    const int mat = r >> 2, h = r & 3;
    const float* Wr = (mat == 0 ? Wb : (mat == 1 ? Wds : Wdl)) + (size_t)h * DD + lane * 16;
    const float4 w0 = *(const float4*)(Wr);
    const float4 w1 = *(const float4*)(Wr + 4);
    const float4 w2 = *(const float4*)(Wr + 8);
    const float4 w3 = *(const float4*)(Wr + 12);
    float p = x0.x*w0.x + x0.y*w0.y + x0.z*w0.z + x0.w*w0.w
            + x1.x*w1.x + x1.y*w1.y + x1.z*w1.z + x1.w*w1.w
            + x2.x*w2.x + x2.y*w2.y + x2.z*w2.z + x2.w*w2.w
            + x3.x*w3.x + x3.y*w3.y + x3.z*w3.z + x3.w*w3.w;
#pragma unroll
    for (int o = 1; o < 64; o <<= 1) p += __shfl_xor(p, o);
    if (lane == 0) res[r] = p;
  }
  __syncthreads();
  if (t < 12) {
    const int mat = t >> 2, h = t & 3;
    float v = res[t];
    if (mat == 1) v += bds[h];
    if (mat == 2) v += bdl[h];
    v = sigm(v);
    const int b = bl >> 12, l = bl & (LL - 1);
    const size_t o = ((size_t)(b*HH + h))*LL + l;
    (mat == 0 ? beta : (mat == 1 ? gs : gl))[o] = v;
  }
}

// ---- hierarchical gate: z bf16, 24 length-512 dots + 2-way softmaxes -------
__global__ __launch_bounds__(256) void gate_kernel(const ushort_t* __restrict__ z,
  const float* __restrict__ Wc, const float* __restrict__ bc,
  const float* __restrict__ Wl, const float* __restrict__ bl_,
  const float* __restrict__ Wg, const float* __restrict__ bg,
  const float* __restrict__ ltc, const float* __restrict__ ltf,
  float* __restrict__ wgt)
{
  const int bl = blockIdx.x;
  const int t = threadIdx.x, wave = t >> 6, lane = t & 63;
  __shared__ float res[24];
  const uint4 zv = *(const uint4*)(z + (size_t)bl * HIDD + lane * 8);
  float zf[8]; unpack8(zv, zf);
  for (int rr = 0; rr < 6; ++rr) {
    const int r = wave * 6 + rr;
    const int mat = r >> 3, qi = r & 7;
    const float* Wr = (mat == 0 ? Wc : (mat == 1 ? Wl : Wg)) + (size_t)qi * HIDD + lane * 8;
    const float4 w0 = *(const float4*)(Wr);
    const float4 w1 = *(const float4*)(Wr + 4);
    float p = zf[0]*w0.x + zf[1]*w0.y + zf[2]*w0.z + zf[3]*w0.w
            + zf[4]*w1.x + zf[5]*w1.y + zf[6]*w1.z + zf[7]*w1.w;
#pragma unroll
    for (int o = 1; o < 64; o <<= 1) p += __shfl_xor(p, o);
    if (lane == 0) {
      const float* br = (mat == 0 ? bc : (mat == 1 ? bl_ : bg));
      res[r] = p + br[qi];
    }
  }
  __syncthreads();
  if (t < 4) {
    const float tc = logf(1.f + __expf(ltc[t])) + 1e-4f;
    const float tf = logf(1.f + __expf(ltf[t])) + 1e-4f;
    const float pg0 = sigm((res[2*t]     - res[2*t+1])     / tc);
    const float q0  = sigm((res[8+2*t]   - res[8+2*t+1])   / tf);
    const float r0  = sigm((res[16+2*t]  - res[16+2*t+1])  / tf);
    float* o = wgt + ((size_t)bl * HH + t) * 4;
    o[0] = pg0 * q0;         o[1] = pg0 * (1.f - q0);
    o[2] = (1.f - pg0) * r0; o[3] = (1.f - pg0) * (1.f - r0);
  }
}

// ---- chunk-local prep (bf16 LDS, stride 264): l2norm, attn, solves ---------
#define QS 264
__global__ __launch_bounds__(256) void prep_kernel(ushort_t* __restrict__ q,
    ushort_t* __restrict__ k, const ushort_t* __restrict__ v,
    const float* __restrict__ beta,
    ushort_t* __restrict__ u, ushort_t* __restrict__ w, float* __restrict__ attn)
{
  __shared__ ushort_t qb[32*QS];
  __shared__ ushort_t kb[32*QS];
  __shared__ float Lm[32*32];
  __shared__ float betas[32];
  const int bid = blockIdx.x;
  const int ci = bid & (NC - 1);
  const int bh = bid >> 7;
  const int t = threadIdx.x;
  const size_t base = ((size_t)bh * LL + ci*32) * DKk;
  if (t < 32) betas[t] = beta[(size_t)bh * LL + ci*32 + t];
  // load 32x256 bf16 tiles (uint4 = 8 bf16)
  for (int i4 = t; i4 < 1024; i4 += 256) {
    const int r = i4 >> 5, e = (i4 & 31) * 8;
    *(uint4*)&qb[r*QS + e] = *(const uint4*)(q + base + r*256 + e);
    *(uint4*)&kb[r*QS + e] = *(const uint4*)(k + base + r*256 + e);
  }
  __syncthreads();
  {  // l2norm rows (8 threads per row)
    const int r = t >> 3, g = t & 7;
    float sq = 0.f, sk = 0.f;
    for (int e = g*32; e < g*32 + 32; ++e) {
      const float a = bf2f(qb[r*QS + e]); sq = fmaf(a, a, sq);
      const float c = bf2f(kb[r*QS + e]); sk = fmaf(c, c, sk);
    }
#pragma unroll
    for (int o = 1; o < 8; o <<= 1) { sq += __shfl_xor(sq, o); sk += __shfl_xor(sk, o); }
    const float rq = rsqrtf(sq + 1e-6f), rk = rsqrtf(sk + 1e-6f);
    for (int e = g*32; e < g*32 + 32; ++e) {
      qb[r*QS + e] = f2bf(bf2f(qb[r*QS + e]) * rq);
      kb[r*QS + e] = f2bf(bf2f(kb[r*QS + e]) * rk);
    }
  }
  __syncthreads();
  // write back normalized q,k
  for (int i4 = t; i4 < 1024; i4 += 256) {
    const int r = i4 >> 5, e = (i4 & 31) * 8;
    *(uint4*)(q + base + r*256 + e) = *(const uint4*)&qb[r*QS + e];
    *(uint4*)(k + base + r*256 + e) = *(const uint4*)&kb[r*QS + e];
  }
  {  // attn (inclusive-tril of q@k^T) and Lm = strict-tril(beta_i * k_i.k_j)
    const int j = t & 31, i0 = (t >> 5) * 4;
#pragma unroll
    for (int ii = 0; ii < 4; ++ii) {
      const int i = i0 + ii;
      float dq = 0.f, dk2 = 0.f;
      for (int e = 0; e < 256; ++e) {
        const float kj = bf2f(kb[j*QS + e]);
        dq  = fmaf(bf2f(qb[i*QS + e]), kj, dq);
        dk2 = fmaf(bf2f(kb[i*QS + e]), kj, dk2);
      }
      attn[((size_t)bh*NC + ci)*1024 + i*32 + j] = (j <= i) ? dq : 0.f;
      Lm[i*32 + j] = (j < i) ? betas[i] * dk2 : 0.f;
    }
  }
  __syncthreads();
  {  // forward substitution per column t: u = Tinv (beta*v), w = Tinv (beta*k)
    float cu[32], cw[32];
#pragma unroll
    for (int r = 0; r < 32; ++r) {
      cu[r] = bf2f(v[base + r*256 + t]) * betas[r];
      cw[r] = bf2f(kb[r*QS + t]) * betas[r];
    }
#pragma unroll
    for (int i = 1; i < 32; ++i) {
      float au = cu[i], aw = cw[i];
#pragma unroll
      for (int j = 0; j < i; ++j) {
        const float lm = Lm[i*32 + j];
        au = fmaf(-lm, cu[j], au);
        aw = fmaf(-lm, cw[j], aw);
      }
      cu[i] = au; cw[i] = aw;
    }
#pragma unroll
    for (int r = 0; r < 32; ++r) {
      u[base + r*256 + t] = f2bf(cu[r]);
      w[base + r*256 + t] = f2bf(cw[r]);
    }
  }
}

// ---- sequential chunk scan with LDS staging + register prefetch ------------
// Per block: (bh, vb) slice of 16 dv columns; S(256x16) in registers.
// Next chunk's w/q/k/u/attn prefetched into registers during compute, then
// committed to LDS (single buffer, 55 KB) behind a barrier.
__global__ __launch_bounds__(256) void scan_kernel(const ushort_t* __restrict__ qn,
  const ushort_t* __restrict__ kn, const ushort_t* __restrict__ u,
  const ushort_t* __restrict__ w, const float* __restrict__ attn,
  float* __restrict__ dout)
{
  __shared__ ushort_t wb[32*256];   // 16 KB
  __shared__ ushort_t qb[32*256];   // 16 KB
  __shared__ ushort_t kb[32*256];   // 16 KB
  __shared__ ushort_t ub[32*16];    // 1 KB
  __shared__ float    ab[32*32];    // 4 KB
  __shared__ float    uhl[32*16];   // 2 KB   -> 55 KB total (<64 KB cap)
  const int bid = blockIdx.x;
  const int vb = bid & 15, bh = bid >> 4;
  const int b = bh >> 2, h = bh & 3;
  const int t = threadIdx.x;
  const int c = t >> 4, g = t & 15;
  const int e0 = g * 16;
  const int dv = vb * 16 + c;
  float S[16];
#pragma unroll
  for (int i = 0; i < 16; ++i) S[i] = 0.f;
  const size_t bhL = (size_t)bh * LL;

  // prefetch registers
  uint4 rw[4], rq[4], rk[4];
  unsigned int ru;
  float4 ra;
  const int ur_ = t >> 3, uc_ = (t & 7) * 2;   // u: 2 bf16 per thread

  auto issue_loads = [&](int ci) {
    const ushort_t* wp = w  + (bhL + (size_t)ci*32) * DKk;
    const ushort_t* qp = qn + (bhL + (size_t)ci*32) * DKk;
    const ushort_t* kp = kn + (bhL + (size_t)ci*32) * DKk;
#pragma unroll
    for (int i = 0; i < 4; ++i) {
      rw[i] = *(const uint4*)(wp + (t + i*256)*8);
      rq[i] = *(const uint4*)(qp + (t + i*256)*8);
      rk[i] = *(const uint4*)(kp + (t + i*256)*8);
    }
    ru = *(const unsigned int*)(u + (bhL + (size_t)ci*32 + ur_)*DVv + vb*16 + uc_);
    ra = *(const float4*)(attn + ((size_t)bh*NC + ci)*1024 + t*4);
  };
  auto commit = [&]() {
#pragma unroll
    for (int i = 0; i < 4; ++i) {
      *(uint4*)&wb[(t + i*256)*8] = rw[i];
      *(uint4*)&qb[(t + i*256)*8] = rq[i];
      *(uint4*)&kb[(t + i*256)*8] = rk[i];
    }
    *(unsigned int*)&ub[t*2] = ru;
    *(float4*)&ab[t*4] = ra;
  };

  issue_loads(0);
  commit();
  __syncthreads();

  for (int ci = 0; ci < NC; ++ci) {
    if (ci + 1 < NC) issue_loads(ci + 1);   // in flight during compute

    // ---- w @ S -> u_hat ----
#pragma unroll 4
    for (int r = 0; r < 32; ++r) {
      const uint4 w0 = *(const uint4*)&wb[r*256 + e0];
      const uint4 w1 = *(const uint4*)&wb[r*256 + e0 + 8];
      float a[16]; unpack8(w0, a); unpack8(w1, a+8);
      float p = 0.f;
#pragma unroll
      for (int i = 0; i < 16; ++i) p = fmaf(a[i], S[i], p);
      p += __shfl_xor(p, 1); p += __shfl_xor(p, 2);
      p += __shfl_xor(p, 4); p += __shfl_xor(p, 8);
      if (g == 0) uhl[r*16 + c] = bf2f(ub[r*16 + c]) - p;
    }
    // ---- q @ S + attn @ u_hat -> output ----
#pragma unroll 4
    for (int r = 0; r < 32; ++r) {
      const uint4 q0 = *(const uint4*)&qb[r*256 + e0];
      const uint4 q1 = *(const uint4*)&qb[r*256 + e0 + 8];
      float a[16]; unpack8(q0, a); unpack8(q1, a+8);
      float p = 0.f;
#pragma unroll
      for (int i = 0; i < 16; ++i) p = fmaf(a[i], S[i], p);
      p = fmaf(ab[r*32 + 2*g],     uhl[(2*g)*16 + c],   p);
      p = fmaf(ab[r*32 + 2*g + 1], uhl[(2*g+1)*16 + c], p);
      p += __shfl_xor(p, 1); p += __shfl_xor(p, 2);
      p += __shfl_xor(p, 4); p += __shfl_xor(p, 8);
      if (g == 0) dout[((size_t)b*LL + ci*32 + r)*DD + h*DVv + dv] = p;
    }
    // ---- S += k^T @ u_hat ----
#pragma unroll 4
    for (int r = 0; r < 32; ++r) {
      const uint4 k0 = *(const uint4*)&kb[r*256 + e0];
      const uint4 k1 = *(const uint4*)&kb[r*256 + e0 + 8];
      float a[16]; unpack8(k0, a); unpack8(k1, a+8);
      const float uh = uhl[r*16 + c];
#pragma unroll
      for (int i = 0; i < 16; ++i) S[i] = fmaf(a[i], uh, S[i]);
    }
    __syncthreads();              // all waves done reading LDS
    if (ci + 1 < NC) commit();    // waits vmcnt, rewrites the buffer
    __syncthreads();              // buffer ready for next chunk
  }
}

// ---- dual EMA scan (bf16 v in, bf16 es/el out) -----------------------------
__global__ __launch_bounds__(64) void ema_kernel(const ushort_t* __restrict__ v,
  const float* __restrict__ gs, const float* __restrict__ gl,
  ushort_t* __restrict__ es, ushort_t* __restrict__ el)
{
  const int bid = blockIdx.x;
  const int vb = bid & 3, bh = bid >> 2;
  const int b = bh >> 2, h = bh & 3;
  const int dv = vb * 64 + threadIdx.x;
  const ushort_t* vp  = v + ((size_t)bh * LL) * DVv + dv;
  const float* gsp = gs + (size_t)bh * LL;
  const float* glp = gl + (size_t)bh * LL;
  ushort_t* esp = es + ((size_t)b * LL) * DD + h*DVv + dv;
  ushort_t* elp = el + ((size_t)b * LL) * DD + h*DVv + dv;
  float s1 = 0.f, s2 = 0.f;
  for (int l = 0; l < LL; ++l) {
    const float vv = bf2f(vp[(size_t)l * DVv]);
    const float a = gsp[l], g2 = glp[l];
    s1 = fmaf(a,  s1, (1.f - a)  * vv);
    s2 = fmaf(g2, s2, (1.f - g2) * vv);
    esp[(size_t)l * DD] = f2bf(s1);
    elp[(size_t)l * DD] = f2bf(s2);
  }
}

// ---- combine + per-head RMSNorm (delta_o fp32 from d_out, rest bf16) -------
__global__ __launch_bounds__(64) void combine_kernel(const ushort_t* __restrict__ v,
  const ushort_t* __restrict__ es, const ushort_t* __restrict__ el,
  const float* __restrict__ dov, const float* __restrict__ wgt,
  const float* __restrict__ onw, ushort_t* __restrict__ outp)
{
  const int bid = blockIdx.x;   // (b*L + l)*H + h
  const int h = bid & 3;
  const size_t bl = (size_t)(bid >> 2);
  const int lane = threadIdx.x;
  const size_t b = bl >> 12;
  const size_t l = bl & (LL - 1);
  const size_t vidx = (((b*HH + h) * (size_t)LL) + l) * DVv + lane*4;
  const size_t didx = bl * DD + h*DVv + lane*4;
  const uint2 vu = *(const uint2*)(v + vidx);
  const uint2 eu = *(const uint2*)(es + didx);
  const uint2 gu = *(const uint2*)(el + didx);
  const float4 d4 = *(const float4*)(dov + didx);
  float vf[4], ef[4], gf[4];
  unpack2(vu.x, vf[0], vf[1]); unpack2(vu.y, vf[2], vf[3]);
  unpack2(eu.x, ef[0], ef[1]); unpack2(eu.y, ef[2], ef[3]);
  unpack2(gu.x, gf[0], gf[1]); unpack2(gu.y, gf[2], gf[3]);
  const float* wp = wgt + (size_t)bid * 4;
  const float w0 = wp[0], w1 = wp[1], w2 = wp[2], w3 = wp[3];
  float o[4];
  const float df[4] = {d4.x, d4.y, d4.z, d4.w};
  float ss = 0.f;
#pragma unroll
  for (int i = 0; i < 4; ++i) {
    o[i] = w0*vf[i] + w1*ef[i] + w2*df[i] + w3*gf[i];
    ss = fmaf(o[i], o[i], ss);
  }
#pragma unroll
  for (int off = 1; off < 64; off <<= 1) ss += __shfl_xor(ss, off);
  const float sc = rsqrtf(ss * (1.f / DVv) + 1e-5f);
  const float4 nw = *(const float4*)(onw + lane*4);
  uint2 pk;
  pk.x = pack2(o[0]*sc*nw.x, o[1]*sc*nw.y);
  pk.y = pack2(o[2]*sc*nw.z, o[3]*sc*nw.w);
  *(uint2*)(outp + didx) = pk;
}

extern "C" void kernel_launch(void* const* d_in, const int* in_sizes, int n_in,
                              void* d_out, int out_size, void* d_ws, size_t ws_size,
                              hipStream_t stream)
{
  const float* x    = (const float*)d_in[0];
  const float* Wq   = (const float*)d_in[1];
  const float* Wk   = (const float*)d_in[2];
  const float* Wv   = (const float*)d_in[3];
  const float* cqw  = (const float*)d_in[4];
  const float* ckw  = (const float*)d_in[5];
  const float* cvw  = (const float*)d_in[6];
  const float* Wb   = (const float*)d_in[7];
  const float* Wds  = (const float*)d_in[8];
  const float* bds  = (const float*)d_in[9];
  const float* Wdl  = (const float*)d_in[10];
  const float* bdl  = (const float*)d_in[11];
  const float* Wtr  = (const float*)d_in[12];
  const float* btr  = (const float*)d_in[13];
  const float* Wc   = (const float*)d_in[14];
  const float* bc   = (const float*)d_in[15];
  const float* Wl   = (const float*)d_in[16];
  const float* blc  = (const float*)d_in[17];
  const float* Wg   = (const float*)d_in[18];
  const float* bg   = (const float*)d_in[19];
  const float* ltc  = (const float*)d_in[20];
  const float* ltf  = (const float*)d_in[21];
  const float* onw  = (const float*)d_in[22];
  const float* Wo   = (const float*)d_in[23];
  float* outp = (float*)d_out;

  // bf16 workspace slabs: peak ~186 MB
  const size_t BLD = (size_t)BB * LL * DD;          // 16.78M elements
  unsigned char* w8 = (unsigned char*)d_ws;
  const size_t SL = BLD * 2;                        // 32 MB bf16 slab
  ushort_t* SA = (ushort_t*)(w8 + 0*SL);   // qraw -> kn          -> opre
  ushort_t* SB = (ushort_t*)(w8 + 1*SL);   // kraw -> vv
  ushort_t* SC = (ushort_t*)(w8 + 2*SL);   // vraw -> u
  ushort_t* SD = (ushort_t*)(w8 + 3*SL);   // qn           -> el
  ushort_t* SE = (ushort_t*)(w8 + 4*SL);   // w            -> es
  ushort_t* zb   = (ushort_t*)(w8 + 5*SL);               // B*L*512 bf16 (16MB)
  float*    attn = (float*)(w8 + 5*SL + BLD);            // 8 MB
  float*    beta = attn + (size_t)BB*HH*NC*1024;
  float*    gs   = beta + (size_t)BB*HH*LL;
  float*    gl   = gs   + (size_t)BB*HH*LL;
  float*    wgt  = gl   + (size_t)BB*HH*LL;              // 1 MB
  float*    dov  = outp;   // delta_o fp32 in d_out until final GEMM

  const int MBL = BB * LL;  // 16384
  dim3 blk256(256);

  gemm_f32_bf16out<0><<<dim3(DD/128, MBL/128), blk256, 0, stream>>>(x, Wq, nullptr, SA, MBL, DD, DD);
  gemm_f32_bf16out<0><<<dim3(DD/128, MBL/128), blk256, 0, stream>>>(x, Wk, nullptr, SB, MBL, DD, DD);
  gemm_f32_bf16out<0><<<dim3(DD/128, MBL/128), blk256, 0, stream>>>(x, Wv, nullptr, SC, MBL, DD, DD);
  gemm_f32_bf16out<1><<<dim3(HIDD/128, MBL/128), blk256, 0, stream>>>(x, Wtr, btr, zb, MBL, HIDD, DD);
  small_proj_kernel<<<dim3(MBL), blk256, 0, stream>>>(x, Wb, Wds, bds, Wdl, bdl, beta, gs, gl);
  gate_kernel<<<dim3(MBL), blk256, 0, stream>>>(zb, Wc, bc, Wl, blc, Wg, bg, ltc, ltf, wgt);
  conv_silu_kernel<<<dim3((unsigned)(BB*LL*DD/256)), blk256, 0, stream>>>(SA, cqw, SD);  // qn=SD
  conv_silu_kernel<<<dim3((unsigned)(BB*LL*DD/256)), blk256, 0, stream>>>(SB, ckw, SA);  // kn=SA
  conv_silu_kernel<<<dim3((unsigned)(BB*LL*DD/256)), blk256, 0, stream>>>(SC, cvw, SB);  // vv=SB
  prep_kernel<<<dim3(BB*HH*NC), blk256, 0, stream>>>(SD, SA, SB, beta, SC, SE, attn);    // u=SC w=SE
  scan_kernel<<<dim3(BB*HH*16), blk256, 0, stream>>>(SD, SA, SC, SE, attn, dov);
  ema_kernel<<<dim3(BB*HH*4), dim3(64), 0, stream>>>(SB, gs, gl, SE, SD);                // es=SE el=SD
  combine_kernel<<<dim3(MBL*HH), dim3(64), 0, stream>>>(SB, SE, SD, dov, wgt, onw, SA);  // opre=SA
  gemm_bf16A_f32out<<<dim3(DD/128, MBL/128), blk256, 0, stream>>>(SA, Wo, outp, MBL, DD, DD);
}

// Round 5
// 4087.704 us; speedup vs baseline: 2.0744x; 1.3963x over previous
//
#include <hip/hip_runtime.h>
#include <math.h>

#define BB 4
#define LL 4096
#define DD 1024
#define HH 4
#define DKk 256
#define DVv 256
#define HIDD 512
#define NC 128   // number of 32-chunks in L

typedef unsigned short ushort_t;
typedef __attribute__((ext_vector_type(8))) short short8;
typedef __attribute__((ext_vector_type(4))) float floatx4;

__device__ __forceinline__ float sigm(float x) { return 1.f / (1.f + __expf(-x)); }

__device__ __forceinline__ float bf2f(ushort_t u) {
  union { unsigned int i; float f; } c; c.i = ((unsigned int)u) << 16; return c.f;
}
__device__ __forceinline__ ushort_t f2bf(float f) {
  union { float f; unsigned int i; } c; c.f = f;
  unsigned int lsb = (c.i >> 16) & 1u;
  return (ushort_t)((c.i + 0x7fffu + lsb) >> 16);
}
__device__ __forceinline__ void unpack2(unsigned int u, float& a, float& b) {
  union { unsigned int i; float f; } c0, c1;
  c0.i = u << 16; c1.i = u & 0xffff0000u; a = c0.f; b = c1.f;
}
__device__ __forceinline__ unsigned int pack2(float a, float b) {
  return (unsigned int)f2bf(a) | ((unsigned int)f2bf(b) << 16);
}
__device__ __forceinline__ void unpack8(const uint4 v, float* o) {
  unpack2(v.x, o[0], o[1]); unpack2(v.y, o[2], o[3]);
  unpack2(v.z, o[4], o[5]); unpack2(v.w, o[6], o[7]);
}

// ---- MFMA GEMM: C(M,N)=A(M,K)@W(N,K)^T. W fp32; A fp32 or bf16 (ABF16). ----
// BF16OUT: C stored bf16 else fp32.  ACT==1: +bias then SiLU.
template<int ACT, int BF16OUT, int ABF16>
__global__ __launch_bounds__(256) void gemm_mfma(const void* __restrict__ Av,
    const float* __restrict__ W, const float* __restrict__ bias,
    void* __restrict__ Cv, int M, int N, int K)
{
  __shared__ ushort_t As[128*32];
  __shared__ ushort_t Ws[128*32];
  const int tid = threadIdx.x;
  const int bm = blockIdx.y * 128, bn = blockIdx.x * 128;
  const int lane = tid & 63, wave = tid >> 6;
  const int wm = (wave >> 1) * 64, wn = (wave & 1) * 64;
  const int fr = lane & 15, fq = lane >> 4;     // frag row / k-quad
  const int sr = tid >> 1, kh = (tid & 1) * 16; // staging: row, k-half
  floatx4 acc[4][4];
#pragma unroll
  for (int i = 0; i < 4; ++i)
#pragma unroll
    for (int j = 0; j < 4; ++j) acc[i][j] = (floatx4){0.f, 0.f, 0.f, 0.f};

  for (int k0 = 0; k0 < K; k0 += 32) {
    uint4 pa0, pa1, pw0, pw1;
    if (ABF16) {
      const ushort_t* Ap = (const ushort_t*)Av + (size_t)(bm + sr) * K + k0 + kh;
      pa0 = *(const uint4*)(Ap);
      pa1 = *(const uint4*)(Ap + 8);
    } else {
      const float* Ap = (const float*)Av + (size_t)(bm + sr) * K + k0 + kh;
      const float4 a0 = *(const float4*)(Ap);     const float4 a1 = *(const float4*)(Ap + 4);
      const float4 a2 = *(const float4*)(Ap + 8); const float4 a3 = *(const float4*)(Ap + 12);
      pa0.x = pack2(a0.x, a0.y); pa0.y = pack2(a0.z, a0.w);
      pa0.z = pack2(a1.x, a1.y); pa0.w = pack2(a1.z, a1.w);
      pa1.x = pack2(a2.x, a2.y); pa1.y = pack2(a2.z, a2.w);
      pa1.z = pack2(a3.x, a3.y); pa1.w = pack2(a3.z, a3.w);
    }
    {
      const float* Wp = W + (size_t)(bn + sr) * K + k0 + kh;
      const float4 w0 = *(const float4*)(Wp);     const float4 w1 = *(const float4*)(Wp + 4);
      const float4 w2 = *(const float4*)(Wp + 8); const float4 w3 = *(const float4*)(Wp + 12);
      pw0.x = pack2(w0.x, w0.y); pw0.y = pack2(w0.z, w0.w);
      pw0.z = pack2(w1.x, w1.y); pw0.w = pack2(w1.z, w1.w);
      pw1.x = pack2(w2.x, w2.y); pw1.y = pack2(w2.z, w2.w);
      pw1.z = pack2(w3.x, w3.y); pw1.w = pack2(w3.z, w3.w);
    }
    __syncthreads();
    *(uint4*)&As[sr*32 + kh]     = pa0;
    *(uint4*)&As[sr*32 + kh + 8] = pa1;
    *(uint4*)&Ws[sr*32 + kh]     = pw0;
    *(uint4*)&Ws[sr*32 + kh + 8] = pw1;
    __syncthreads();
    short8 af[4], bf_[4];
#pragma unroll
    for (int mt = 0; mt < 4; ++mt)
      af[mt] = *(const short8*)&As[(wm + mt*16 + fr)*32 + fq*8];
#pragma unroll
    for (int nt = 0; nt < 4; ++nt)
      bf_[nt] = *(const short8*)&Ws[(wn + nt*16 + fr)*32 + fq*8];
#pragma unroll
    for (int mt = 0; mt < 4; ++mt)
#pragma unroll
      for (int nt = 0; nt < 4; ++nt)
        acc[mt][nt] = __builtin_amdgcn_mfma_f32_16x16x32_bf16(af[mt], bf_[nt], acc[mt][nt], 0, 0, 0);
  }
#pragma unroll
  for (int mt = 0; mt < 4; ++mt) {
#pragma unroll
    for (int reg = 0; reg < 4; ++reg) {
      const int row = bm + wm + mt*16 + fq*4 + reg;
#pragma unroll
      for (int nt = 0; nt < 4; ++nt) {
        const int col = bn + wn + nt*16 + fr;
        float v = acc[mt][nt][reg];
        if (ACT == 1) { v += bias[col]; v = v * sigm(v); }
        if (BF16OUT) ((ushort_t*)Cv)[(size_t)row * N + col] = f2bf(v);
        else         ((float*)Cv)[(size_t)row * N + col] = v;
      }
    }
  }
}

// ---- depthwise causal conv(k=4)+SiLU, bf16 in/out, relayout to (B,H,L,DK) --
__global__ __launch_bounds__(256) void conv_silu_kernel(const ushort_t* __restrict__ xin,
    const float* __restrict__ wc, ushort_t* __restrict__ outp)
{
  const size_t idx = (size_t)blockIdx.x * 256 + threadIdx.x;  // over B*L*D
  const int d = (int)(idx & (DD - 1));
  const int l = (int)((idx >> 10) & (LL - 1));
  const float4 w = *(const float4*)(wc + d * 4);
  const ushort_t* xp = xin + idx;
  float acc = w.w * bf2f(xp[0]);
  if (l >= 1) acc += w.z * bf2f(xp[-DD]);
  if (l >= 2) acc += w.y * bf2f(xp[-2*DD]);
  if (l >= 3) acc += w.x * bf2f(xp[-3*DD]);
  acc = acc * sigm(acc);
  const int b = (int)(idx >> 22);
  const int h = d >> 8, dk = d & 255;
  outp[(((size_t)(b*HH + h))*LL + l)*DKk + dk] = f2bf(acc);
}

// ---- beta / g_s / g_l: 12 length-1024 dots per (b,l), x fp32 ---------------
__global__ __launch_bounds__(256) void small_proj_kernel(const float* __restrict__ x,
   const float* __restrict__ Wb, const float* __restrict__ Wds, const float* __restrict__ bds,
   const float* __restrict__ Wdl, const float* __restrict__ bdl,
   float* __restrict__ beta, float* __restrict__ gs, float* __restrict__ gl)
{
  const int bl = blockIdx.x;
  const int t = threadIdx.x, wave = t >> 6, lane = t & 63;
  __shared__ float res[12];
  const float* xr = x + (size_t)bl * DD + lane * 16;
  const float4 x0 = *(const float4*)(xr);
  const float4 x1 = *(const float4*)(xr + 4);
  const float4 x2 = *(const float4*)(xr + 8);
  const float4 x3 = *(const float4*)(xr + 12);
  for (int rr = 0; rr < 3; ++rr) {
    const int r = wave * 3 + rr;
    const int mat = r >> 2, h = r & 3;
    const float* Wr = (mat == 0 ? Wb : (mat == 1 ? Wds : Wdl)) + (size_t)h * DD + lane * 16;
    const float4 w0 = *(const float4*)(Wr);
    const float4 w1 = *(const float4*)(Wr + 4);
    const float4 w2 = *(const float4*)(Wr + 8);
    const float4 w3 = *(const float4*)(Wr + 12);
    float p = x0.x*w0.x + x0.y*w0.y + x0.z*w0.z + x0.w*w0.w
            + x1.x*w1.x + x1.y*w1.y + x1.z*w1.z + x1.w*w1.w
            + x2.x*w2.x + x2.y*w2.y + x2.z*w2.z + x2.w*w2.w
            + x3.x*w3.x + x3.y*w3.y + x3.z*w3.z + x3.w*w3.w;
#pragma unroll
    for (int o = 1; o < 64; o <<= 1) p += __shfl_xor(p, o);
    if (lane == 0) res[r] = p;
  }
  __syncthreads();
  if (t < 12) {
    const int mat = t >> 2, h = t & 3;
    float v = res[t];
    if (mat == 1) v += bds[h];
    if (mat == 2) v += bdl[h];
    v = sigm(v);
    const int b = bl >> 12, l = bl & (LL - 1);
    const size_t o = ((size_t)(b*HH + h))*LL + l;
    (mat == 0 ? beta : (mat == 1 ? gs : gl))[o] = v;
  }
}

// ---- hierarchical gate: z bf16, 24 length-512 dots + 2-way softmaxes -------
__global__ __launch_bounds__(256) void gate_kernel(const ushort_t* __restrict__ z,
  const float* __restrict__ Wc, const float* __restrict__ bc,
  const float* __restrict__ Wl, const float* __restrict__ bl_,
  const float* __restrict__ Wg, const float* __restrict__ bg,
  const float* __restrict__ ltc, const float* __restrict__ ltf,
  float* __restrict__ wgt)
{
  const int bl = blockIdx.x;
  const int t = threadIdx.x, wave = t >> 6, lane = t & 63;
  __shared__ float res[24];
  const uint4 zv = *(const uint4*)(z + (size_t)bl * HIDD + lane * 8);
  float zf[8]; unpack8(zv, zf);
  for (int rr = 0; rr < 6; ++rr) {
    const int r = wave * 6 + rr;
    const int mat = r >> 3, qi = r & 7;
    const float* Wr = (mat == 0 ? Wc : (mat == 1 ? Wl : Wg)) + (size_t)qi * HIDD + lane * 8;
    const float4 w0 = *(const float4*)(Wr);
    const float4 w1 = *(const float4*)(Wr + 4);
    float p = zf[0]*w0.x + zf[1]*w0.y + zf[2]*w0.z + zf[3]*w0.w
            + zf[4]*w1.x + zf[5]*w1.y + zf[6]*w1.z + zf[7]*w1.w;
#pragma unroll
    for (int o = 1; o < 64; o <<= 1) p += __shfl_xor(p, o);
    if (lane == 0) {
      const float* br = (mat == 0 ? bc : (mat == 1 ? bl_ : bg));
      res[r] = p + br[qi];
    }
  }
  __syncthreads();
  if (t < 4) {
    const float tc = logf(1.f + __expf(ltc[t])) + 1e-4f;
    const float tf = logf(1.f + __expf(ltf[t])) + 1e-4f;
    const float pg0 = sigm((res[2*t]     - res[2*t+1])     / tc);
    const float q0  = sigm((res[8+2*t]   - res[8+2*t+1])   / tf);
    const float r0  = sigm((res[16+2*t]  - res[16+2*t+1])  / tf);
    float* o = wgt + ((size_t)bl * HH + t) * 4;
    o[0] = pg0 * q0;         o[1] = pg0 * (1.f - q0);
    o[2] = (1.f - pg0) * r0; o[3] = (1.f - pg0) * (1.f - r0);
  }
}

// ---- chunk-local prep (bf16 LDS, stride 264): l2norm, attn, solves ---------
#define QS 264
__global__ __launch_bounds__(256) void prep_kernel(ushort_t* __restrict__ q,
    ushort_t* __restrict__ k, const ushort_t* __restrict__ v,
    const float* __restrict__ beta,
    ushort_t* __restrict__ u, ushort_t* __restrict__ w, float* __restrict__ attn)
{
  __shared__ ushort_t qb[32*QS];
  __shared__ ushort_t kb[32*QS];
  __shared__ float Lm[32*32];
  __shared__ float betas[32];
  const int bid = blockIdx.x;
  const int ci = bid & (NC - 1);
  const int bh = bid >> 7;
  const int t = threadIdx.x;
  const size_t base = ((size_t)bh * LL + ci*32) * DKk;
  if (t < 32) betas[t] = beta[(size_t)bh * LL + ci*32 + t];
  for (int i4 = t; i4 < 1024; i4 += 256) {
    const int r = i4 >> 5, e = (i4 & 31) * 8;
    *(uint4*)&qb[r*QS + e] = *(const uint4*)(q + base + r*256 + e);
    *(uint4*)&kb[r*QS + e] = *(const uint4*)(k + base + r*256 + e);
  }
  __syncthreads();
  {
    const int r = t >> 3, g = t & 7;
    float sq = 0.f, sk = 0.f;
    for (int e = g*32; e < g*32 + 32; ++e) {
      const float a = bf2f(qb[r*QS + e]); sq = fmaf(a, a, sq);
      const float c = bf2f(kb[r*QS + e]); sk = fmaf(c, c, sk);
    }
#pragma unroll
    for (int o = 1; o < 8; o <<= 1) { sq += __shfl_xor(sq, o); sk += __shfl_xor(sk, o); }
    const float rq = rsqrtf(sq + 1e-6f), rk = rsqrtf(sk + 1e-6f);
    for (int e = g*32; e < g*32 + 32; ++e) {
      qb[r*QS + e] = f2bf(bf2f(qb[r*QS + e]) * rq);
      kb[r*QS + e] = f2bf(bf2f(kb[r*QS + e]) * rk);
    }
  }
  __syncthreads();
  for (int i4 = t; i4 < 1024; i4 += 256) {
    const int r = i4 >> 5, e = (i4 & 31) * 8;
    *(uint4*)(q + base + r*256 + e) = *(const uint4*)&qb[r*QS + e];
    *(uint4*)(k + base + r*256 + e) = *(const uint4*)&kb[r*QS + e];
  }
  {
    const int j = t & 31, i0 = (t >> 5) * 4;
#pragma unroll
    for (int ii = 0; ii < 4; ++ii) {
      const int i = i0 + ii;
      float dq = 0.f, dk2 = 0.f;
      for (int e = 0; e < 256; ++e) {
        const float kj = bf2f(kb[j*QS + e]);
        dq  = fmaf(bf2f(qb[i*QS + e]), kj, dq);
        dk2 = fmaf(bf2f(kb[i*QS + e]), kj, dk2);
      }
      attn[((size_t)bh*NC + ci)*1024 + i*32 + j] = (j <= i) ? dq : 0.f;
      Lm[i*32 + j] = (j < i) ? betas[i] * dk2 : 0.f;
    }
  }
  __syncthreads();
  {
    float cu[32], cw[32];
#pragma unroll
    for (int r = 0; r < 32; ++r) {
      cu[r] = bf2f(v[base + r*256 + t]) * betas[r];
      cw[r] = bf2f(kb[r*QS + t]) * betas[r];
    }
#pragma unroll
    for (int i = 1; i < 32; ++i) {
      float au = cu[i], aw = cw[i];
#pragma unroll
      for (int j = 0; j < i; ++j) {
        const float lm = Lm[i*32 + j];
        au = fmaf(-lm, cu[j], au);
        aw = fmaf(-lm, cw[j], aw);
      }
      cu[i] = au; cw[i] = aw;
    }
#pragma unroll
    for (int r = 0; r < 32; ++r) {
      u[base + r*256 + t] = f2bf(cu[r]);
      w[base + r*256 + t] = f2bf(cw[r]);
    }
  }
}

// ---- sequential chunk scan: 512 blocks (2/CU), 8 dv per block --------------
__global__ __launch_bounds__(256) void scan_kernel(const ushort_t* __restrict__ qn,
  const ushort_t* __restrict__ kn, const ushort_t* __restrict__ u,
  const ushort_t* __restrict__ w, const float* __restrict__ attn,
  float* __restrict__ dout)
{
  __shared__ ushort_t wb[32*256];   // 16 KB
  __shared__ ushort_t qb[32*256];   // 16 KB
  __shared__ ushort_t kb[32*256];   // 16 KB
  __shared__ ushort_t ub[32*8];     // 512 B
  __shared__ float    ab[32*32];    // 4 KB
  __shared__ float    uhl[8*32];    // 1 KB  [c][j]
  const int bid = blockIdx.x;
  const int vs = bid & 31, bh = bid >> 5;
  const int b = bh >> 2, h = bh & 3;
  const int t = threadIdx.x;
  const int c = t >> 5, g = t & 31;
  const int e0 = g * 8;
  const int dv = vs * 8 + c;
  float S[8];
#pragma unroll
  for (int i = 0; i < 8; ++i) S[i] = 0.f;
  const size_t bhL = (size_t)bh * LL;

  uint4 rw[4], rq[4], rk[4];
  unsigned int ru = 0;
  float4 ra;
  const int ur_ = t >> 2, uc_ = (t & 3) * 2;

  auto issue_loads = [&](int ci) {
    const ushort_t* wp = w  + (bhL + (size_t)ci*32) * DKk;
    const ushort_t* qp = qn + (bhL + (size_t)ci*32) * DKk;
    const ushort_t* kp = kn + (bhL + (size_t)ci*32) * DKk;
#pragma unroll
    for (int i = 0; i < 4; ++i) {
      rw[i] = *(const uint4*)(wp + (t + i*256)*8);
      rq[i] = *(const uint4*)(qp + (t + i*256)*8);
      rk[i] = *(const uint4*)(kp + (t + i*256)*8);
    }
    if (t < 128)
      ru = *(const unsigned int*)(u + (bhL + (size_t)ci*32 + ur_)*DVv + vs*8 + uc_);
    ra = *(const float4*)(attn + ((size_t)bh*NC + ci)*1024 + t*4);
  };
  auto commit = [&]() {
#pragma unroll
    for (int i = 0; i < 4; ++i) {
      *(uint4*)&wb[(t + i*256)*8] = rw[i];
      *(uint4*)&qb[(t + i*256)*8] = rq[i];
      *(uint4*)&kb[(t + i*256)*8] = rk[i];
    }
    if (t < 128) *(unsigned int*)&ub[ur_*8 + uc_] = ru;
    *(float4*)&ab[t*4] = ra;
  };

  issue_loads(0);
  commit();
  __syncthreads();

  for (int ci = 0; ci < NC; ++ci) {
    if (ci + 1 < NC) issue_loads(ci + 1);

#pragma unroll 4
    for (int r = 0; r < 32; ++r) {
      const uint4 wv = *(const uint4*)&wb[r*256 + e0];
      float a[8]; unpack8(wv, a);
      float p0 = a[0]*S[0], p1 = a[1]*S[1];
      p0 = fmaf(a[2], S[2], p0); p1 = fmaf(a[3], S[3], p1);
      p0 = fmaf(a[4], S[4], p0); p1 = fmaf(a[5], S[5], p1);
      p0 = fmaf(a[6], S[6], p0); p1 = fmaf(a[7], S[7], p1);
      float p = p0 + p1;
      p += __shfl_xor(p, 1);  p += __shfl_xor(p, 2);
      p += __shfl_xor(p, 4);  p += __shfl_xor(p, 8); p += __shfl_xor(p, 16);
      if (g == 0) uhl[c*32 + r] = bf2f(ub[r*8 + c]) - p;
    }
#pragma unroll 4
    for (int r = 0; r < 32; ++r) {
      const uint4 qv = *(const uint4*)&qb[r*256 + e0];
      float a[8]; unpack8(qv, a);
      float p0 = a[0]*S[0], p1 = a[1]*S[1];
      p0 = fmaf(a[2], S[2], p0); p1 = fmaf(a[3], S[3], p1);
      p0 = fmaf(a[4], S[4], p0); p1 = fmaf(a[5], S[5], p1);
      p0 = fmaf(a[6], S[6], p0); p1 = fmaf(a[7], S[7], p1);
      float p = fmaf(ab[r*32 + g], uhl[c*32 + g], p0 + p1);
      p += __shfl_xor(p, 1);  p += __shfl_xor(p, 2);
      p += __shfl_xor(p, 4);  p += __shfl_xor(p, 8); p += __shfl_xor(p, 16);
      if (g == 0) dout[((size_t)b*LL + ci*32 + r)*DD + h*DVv + dv] = p;
    }
#pragma unroll 4
    for (int r = 0; r < 32; ++r) {
      const uint4 kv = *(const uint4*)&kb[r*256 + e0];
      float a[8]; unpack8(kv, a);
      const float uh = uhl[c*32 + r];
#pragma unroll
      for (int i = 0; i < 8; ++i) S[i] = fmaf(a[i], uh, S[i]);
    }
    __syncthreads();
    if (ci + 1 < NC) commit();
    __syncthreads();
  }
}

// ---- dual EMA scan (bf16 v in, bf16 es/el out) -----------------------------
__global__ __launch_bounds__(64) void ema_kernel(const ushort_t* __restrict__ v,
  const float* __restrict__ gs, const float* __restrict__ gl,
  ushort_t* __restrict__ es, ushort_t* __restrict__ el)
{
  const int bid = blockIdx.x;
  const int vb = bid & 3, bh = bid >> 2;
  const int b = bh >> 2, h = bh & 3;
  const int dv = vb * 64 + threadIdx.x;
  const ushort_t* vp  = v + ((size_t)bh * LL) * DVv + dv;
  const float* gsp = gs + (size_t)bh * LL;
  const float* glp = gl + (size_t)bh * LL;
  ushort_t* esp = es + ((size_t)b * LL) * DD + h*DVv + dv;
  ushort_t* elp = el + ((size_t)b * LL) * DD + h*DVv + dv;
  float s1 = 0.f, s2 = 0.f;
  for (int l = 0; l < LL; ++l) {
    const float vv = bf2f(vp[(size_t)l * DVv]);
    const float a = gsp[l], g2 = glp[l];
    s1 = fmaf(a,  s1, (1.f - a)  * vv);
    s2 = fmaf(g2, s2, (1.f - g2) * vv);
    esp[(size_t)l * DD] = f2bf(s1);
    elp[(size_t)l * DD] = f2bf(s2);
  }
}

// ---- combine + per-head RMSNorm (delta_o fp32 from d_out, rest bf16) -------
__global__ __launch_bounds__(64) void combine_kernel(const ushort_t* __restrict__ v,
  const ushort_t* __restrict__ es, const ushort_t* __restrict__ el,
  const float* __restrict__ dov, const float* __restrict__ wgt,
  const float* __restrict__ onw, ushort_t* __restrict__ outp)
{
  const int bid = blockIdx.x;
  const int h = bid & 3;
  const size_t bl = (size_t)(bid >> 2);
  const int lane = threadIdx.x;
  const size_t b = bl >> 12;
  const size_t l = bl & (LL - 1);
  const size_t vidx = (((b*HH + h) * (size_t)LL) + l) * DVv + lane*4;
  const size_t didx = bl * DD + h*DVv + lane*4;
  const uint2 vu = *(const uint2*)(v + vidx);
  const uint2 eu = *(const uint2*)(es + didx);
  const uint2 gu = *(const uint2*)(el + didx);
  const float4 d4 = *(const float4*)(dov + didx);
  float vf[4], ef[4], gf[4];
  unpack2(vu.x, vf[0], vf[1]); unpack2(vu.y, vf[2], vf[3]);
  unpack2(eu.x, ef[0], ef[1]); unpack2(eu.y, ef[2], ef[3]);
  unpack2(gu.x, gf[0], gf[1]); unpack2(gu.y, gf[2], gf[3]);
  const float* wp = wgt + (size_t)bid * 4;
  const float w0 = wp[0], w1 = wp[1], w2 = wp[2], w3 = wp[3];
  float o[4];
  const float df[4] = {d4.x, d4.y, d4.z, d4.w};
  float ss = 0.f;
#pragma unroll
  for (int i = 0; i < 4; ++i) {
    o[i] = w0*vf[i] + w1*ef[i] + w2*df[i] + w3*gf[i];
    ss = fmaf(o[i], o[i], ss);
  }
#pragma unroll
  for (int off = 1; off < 64; off <<= 1) ss += __shfl_xor(ss, off);
  const float sc = rsqrtf(ss * (1.f / DVv) + 1e-5f);
  const float4 nw = *(const float4*)(onw + lane*4);
  uint2 pk;
  pk.x = pack2(o[0]*sc*nw.x, o[1]*sc*nw.y);
  pk.y = pack2(o[2]*sc*nw.z, o[3]*sc*nw.w);
  *(uint2*)(outp + didx) = pk;
}

extern "C" void kernel_launch(void* const* d_in, const int* in_sizes, int n_in,
                              void* d_out, int out_size, void* d_ws, size_t ws_size,
                              hipStream_t stream)
{
  const float* x    = (const float*)d_in[0];
  const float* Wq   = (const float*)d_in[1];
  const float* Wk   = (const float*)d_in[2];
  const float* Wv   = (const float*)d_in[3];
  const float* cqw  = (const float*)d_in[4];
  const float* ckw  = (const float*)d_in[5];
  const float* cvw  = (const float*)d_in[6];
  const float* Wb   = (const float*)d_in[7];
  const float* Wds  = (const float*)d_in[8];
  const float* bds  = (const float*)d_in[9];
  const float* Wdl  = (const float*)d_in[10];
  const float* bdl  = (const float*)d_in[11];
  const float* Wtr  = (const float*)d_in[12];
  const float* btr  = (const float*)d_in[13];
  const float* Wc   = (const float*)d_in[14];
  const float* bc   = (const float*)d_in[15];
  const float* Wl   = (const float*)d_in[16];
  const float* blc  = (const float*)d_in[17];
  const float* Wg   = (const float*)d_in[18];
  const float* bg   = (const float*)d_in[19];
  const float* ltc  = (const float*)d_in[20];
  const float* ltf  = (const float*)d_in[21];
  const float* onw  = (const float*)d_in[22];
  const float* Wo   = (const float*)d_in[23];
  float* outp = (float*)d_out;

  const size_t BLD = (size_t)BB * LL * DD;
  unsigned char* w8 = (unsigned char*)d_ws;
  const size_t SL = BLD * 2;                        // 32 MB bf16 slab
  ushort_t* SA = (ushort_t*)(w8 + 0*SL);   // qraw -> kn -> opre
  ushort_t* SB = (ushort_t*)(w8 + 1*SL);   // kraw -> vv
  ushort_t* SC = (ushort_t*)(w8 + 2*SL);   // vraw -> u
  ushort_t* SD = (ushort_t*)(w8 + 3*SL);   // qn -> el
  ushort_t* SE = (ushort_t*)(w8 + 4*SL);   // w  -> es
  ushort_t* zb   = (ushort_t*)(w8 + 5*SL);
  float*    attn = (float*)(w8 + 5*SL + BLD);
  float*    beta = attn + (size_t)BB*HH*NC*1024;
  float*    gs   = beta + (size_t)BB*HH*LL;
  float*    gl   = gs   + (size_t)BB*HH*LL;
  float*    wgt  = gl   + (size_t)BB*HH*LL;
  float*    dov  = outp;

  const int MBL = BB * LL;  // 16384
  dim3 blk256(256);

  gemm_mfma<0,1,0><<<dim3(DD/128, MBL/128), blk256, 0, stream>>>(x, Wq, nullptr, SA, MBL, DD, DD);
  gemm_mfma<0,1,0><<<dim3(DD/128, MBL/128), blk256, 0, stream>>>(x, Wk, nullptr, SB, MBL, DD, DD);
  gemm_mfma<0,1,0><<<dim3(DD/128, MBL/128), blk256, 0, stream>>>(x, Wv, nullptr, SC, MBL, DD, DD);
  gemm_mfma<1,1,0><<<dim3(HIDD/128, MBL/128), blk256, 0, stream>>>(x, Wtr, btr, zb, MBL, HIDD, DD);
  small_proj_kernel<<<dim3(MBL), blk256, 0, stream>>>(x, Wb, Wds, bds, Wdl, bdl, beta, gs, gl);
  gate_kernel<<<dim3(MBL), blk256, 0, stream>>>(zb, Wc, bc, Wl, blc, Wg, bg, ltc, ltf, wgt);
  conv_silu_kernel<<<dim3((unsigned)(BB*LL*DD/256)), blk256, 0, stream>>>(SA, cqw, SD);  // qn=SD
  conv_silu_kernel<<<dim3((unsigned)(BB*LL*DD/256)), blk256, 0, stream>>>(SB, ckw, SA);  // kn=SA
  conv_silu_kernel<<<dim3((unsigned)(BB*LL*DD/256)), blk256, 0, stream>>>(SC, cvw, SB);  // vv=SB
  prep_kernel<<<dim3(BB*HH*NC), blk256, 0, stream>>>(SD, SA, SB, beta, SC, SE, attn);    // u=SC w=SE
  scan_kernel<<<dim3(BB*HH*32), blk256, 0, stream>>>(SD, SA, SC, SE, attn, dov);
  ema_kernel<<<dim3(BB*HH*4), dim3(64), 0, stream>>>(SB, gs, gl, SE, SD);                // es=SE el=SD
  combine_kernel<<<dim3(MBL*HH), dim3(64), 0, stream>>>(SB, SE, SD, dov, wgt, onw, SA);  // opre=SA
  gemm_mfma<0,0,1><<<dim3(DD/128, MBL/128), blk256, 0, stream>>>(SA, Wo, nullptr, outp, MBL, DD, DD);
}